// Round 3
// baseline (309.715 us; speedup 1.0000x reference)
//
#include <hip/hip_runtime.h>

// DSR loss: R_t = sum_i w[t,i]*x[t,i];  A_t = c*A_{t-1} + eta*R_t (c=0.99),
// B_t likewise with R^2;  D_t from (A_prev,B_prev);  out = -sum(D)/B.
//
// R3: K1 = streaming dots with 16-deep MLP (arrayed float4 loads) + fused
// per-chunk affine aggregate (was K2). K3 scans chunk aggregates, K4 replays
// computing D, K5 reduces. fp64 internal math (bit-exact vs ref in R1/R2).

#define D_ETA 0.01
#define D_C   (1.0 - D_ETA)
#define D_EPS 1e-8

constexpr int BLOCK = 256;
constexpr int K1_IT = 8;             // row-groups of 64 per block
constexpr int CHUNK = K1_IT * 64;    // 512 rows per block = scan chunk
constexpr int LPT   = CHUNK / BLOCK; // 2 rows per thread in scan phase

// fallback (ws too small): fp64 dot for one row
__device__ __forceinline__ float row_R(const float* __restrict__ w,
                                       const float* __restrict__ x,
                                       long long row) {
    const float4* w4 = (const float4*)(w + row * 16);
    const float4* x4 = (const float4*)(x + row * 16);
    double r = 0.0;
#pragma unroll
    for (int q = 0; q < 4; ++q) {
        float4 a = w4[q];
        float4 b = x4[q];
        r += (double)a.x * (double)b.x;
        r += (double)a.y * (double)b.y;
        r += (double)a.z * (double)b.z;
        r += (double)a.w * (double)b.w;
    }
    return (float)r;
}

__device__ __forceinline__ double dot4d(float4 a, float4 b) {
    return (double)a.x * (double)b.x + (double)a.y * (double)b.y
         + (double)a.z * (double)b.z + (double)a.w * (double)b.w;
}

// Hillis-Steele inclusive scan over 256 affine transforms (m, sA, sB).
__device__ __forceinline__ void block_scan(double& m, double& sA, double& sB,
                                           double* mS, double* aS, double* bS) {
    int tid = threadIdx.x;
    mS[tid] = m; aS[tid] = sA; bS[tid] = sB;
    __syncthreads();
#pragma unroll
    for (int off = 1; off < BLOCK; off <<= 1) {
        double pm = 1.0, pa = 0.0, pb = 0.0;
        if (tid >= off) { pm = mS[tid - off]; pa = aS[tid - off]; pb = bS[tid - off]; }
        __syncthreads();
        if (tid >= off) {
            sA = m * pa + sA;
            sB = m * pb + sB;
            m  = pm * m;
        }
        mS[tid] = m; aS[tid] = sA; bS[tid] = sB;
        __syncthreads();
    }
}

// ---------------- K1: streaming dots + chunk aggregate ----------------
// 4 lanes per row; per iter a wave loads 64 consecutive float4 (1 KB/instr).
// 8 iters arrayed -> 16 independent dwordx4 in flight per wave before any
// dependent op (vs 2 in R2 -- the R2 latency wall). Then R round-trips
// through LDS so each thread owns 2 consecutive rows for the affine
// aggregate; block_scan produces the chunk transform (was kernel K2).
__global__ __launch_bounds__(BLOCK) void k1_dots_agg(
    const float* __restrict__ w, const float* __restrict__ x, int nrows,
    float* __restrict__ R,
    double* __restrict__ blkM, double* __restrict__ blkA, double* __restrict__ blkB)
{
    __shared__ float Rs[CHUNK];
    __shared__ double mS[BLOCK], aS[BLOCK], bS[BLOCK];
    int tid = threadIdx.x;
    int q    = tid & 3;
    int rsub = tid >> 2;
    long long base = (long long)blockIdx.x * CHUNK;
    const float4* w4 = (const float4*)w;
    const float4* x4 = (const float4*)x;
    long long f0 = base * 4 + tid;

    double p[K1_IT];
    if (base + CHUNK <= (long long)nrows) {
        float4 a[K1_IT], b[K1_IT];
#pragma unroll
        for (int it = 0; it < K1_IT; ++it) a[it] = w4[f0 + it * 256];
#pragma unroll
        for (int it = 0; it < K1_IT; ++it) b[it] = x4[f0 + it * 256];
#pragma unroll
        for (int it = 0; it < K1_IT; ++it) p[it] = dot4d(a[it], b[it]);
    } else {
#pragma unroll
        for (int it = 0; it < K1_IT; ++it) {
            long long row = base + it * 64 + rsub;
            p[it] = 0.0;
            if (row < nrows) {
                float4 a = w4[row * 4 + q];
                float4 b = x4[row * 4 + q];
                p[it] = dot4d(a, b);
            }
        }
    }

#pragma unroll
    for (int it = 0; it < K1_IT; ++it) {
        p[it] += __shfl_xor(p[it], 1, 64);
        p[it] += __shfl_xor(p[it], 2, 64);
    }

    if (q == 0) {
#pragma unroll
        for (int it = 0; it < K1_IT; ++it) {
            long long row = base + it * 64 + rsub;
            float rf = (float)p[it];
            Rs[it * 64 + rsub] = rf;
            if (row < nrows) R[row] = rf;
        }
    }
    __syncthreads();

    // chunk aggregate: thread owns rows [tid*LPT, tid*LPT+LPT)
    int start = tid * LPT;
    long long g = base + start;
    long long rem = (long long)nrows - g;
    int len = rem >= LPT ? LPT : (rem > 0 ? (int)rem : 0);

    double m = 1.0, sA = 0.0, sB = 0.0;
    for (int k = 0; k < len; ++k) {
        double r = (double)Rs[start + k];
        sA = D_C * sA + D_ETA * r;
        sB = D_C * sB + D_ETA * (r * r);
        m *= D_C;
    }
    block_scan(m, sA, sB, mS, aS, bS);
    if (tid == BLOCK - 1) {
        blkM[blockIdx.x] = m;
        blkA[blockIdx.x] = sA;
        blkB[blockIdx.x] = sB;
    }
}

// ---------------- K2 (fallback only, ws too small): chunk aggregates ----
__global__ __launch_bounds__(BLOCK) void k2_partials_fb(
    const float* __restrict__ w, const float* __restrict__ x, int nrows,
    double* __restrict__ blkM, double* __restrict__ blkA, double* __restrict__ blkB)
{
    __shared__ double mS[BLOCK], aS[BLOCK], bS[BLOCK];
    int tid = threadIdx.x;
    long long g0 = (long long)blockIdx.x * CHUNK + (long long)tid * LPT;
    long long rem = (long long)nrows - g0;
    int len = rem >= LPT ? LPT : (rem > 0 ? (int)rem : 0);

    double m = 1.0, sA = 0.0, sB = 0.0;
    for (int k = 0; k < len; ++k) {
        double r = (double)row_R(w, x, g0 + k);
        sA = D_C * sA + D_ETA * r;
        sB = D_C * sB + D_ETA * (r * r);
        m *= D_C;
    }
    block_scan(m, sA, sB, mS, aS, bS);
    if (tid == BLOCK - 1) {
        blkM[blockIdx.x] = m;
        blkA[blockIdx.x] = sA;
        blkB[blockIdx.x] = sB;
    }
}

// ---------------- K3: scan of chunk aggregates (1 block) ----------------
__global__ __launch_bounds__(BLOCK) void k3_scan(
    int nb,
    const double* __restrict__ blkM, const double* __restrict__ blkA,
    const double* __restrict__ blkB,
    double* __restrict__ A0, double* __restrict__ B0)
{
    __shared__ double mS[BLOCK], aS[BLOCK], bS[BLOCK];
    int tid = threadIdx.x;
    int K = (nb + BLOCK - 1) / BLOCK;
    int g0 = tid * K;
    int g1 = g0 + K; if (g1 > nb) g1 = nb;

    double m = 1.0, sA = 0.0, sB = 0.0;
    for (int g = g0; g < g1; ++g) {
        double mg = blkM[g], ag = blkA[g], bg = blkB[g];
        sA = mg * sA + ag;
        sB = mg * sB + bg;
        m *= mg;
    }
    block_scan(m, sA, sB, mS, aS, bS);

    double em = 1.0, ea = 0.0, eb = 0.0;
    if (tid > 0) { em = mS[tid - 1]; ea = aS[tid - 1]; eb = bS[tid - 1]; }
    double A = ea;                 // em*0 + ea
    double B = em * D_EPS + eb;
    for (int g = g0; g < g1; ++g) {
        A0[g] = A; B0[g] = B;
        double mg = blkM[g], ag = blkA[g], bg = blkB[g];
        A = mg * A + ag;
        B = mg * B + bg;
    }
}

// ---------------- K4: replay + D sum ----------------
__global__ __launch_bounds__(BLOCK) void k4_dsum(
    const float* __restrict__ Rws,
    const float* __restrict__ w, const float* __restrict__ x, int nrows,
    const double* __restrict__ A0, const double* __restrict__ B0,
    double* __restrict__ bsum)
{
    __shared__ double mS[BLOCK], aS[BLOCK], bS[BLOCK];
    __shared__ double wsum[BLOCK / 64];
    int tid = threadIdx.x;
    long long g0 = (long long)blockIdx.x * CHUNK + (long long)tid * LPT;
    long long rem = (long long)nrows - g0;
    int len = rem >= LPT ? LPT : (rem > 0 ? (int)rem : 0);

    float rv[LPT];
    if (Rws) {
        if (len == LPT) {
            float2 u = *(const float2*)(Rws + g0);
            rv[0] = u.x; rv[1] = u.y;
        } else {
            for (int k = 0; k < len; ++k) rv[k] = Rws[g0 + k];
        }
    } else {
        for (int k = 0; k < len; ++k) rv[k] = row_R(w, x, g0 + k);
    }

    double m = 1.0, sA = 0.0, sB = 0.0;
    for (int k = 0; k < len; ++k) {
        double r = (double)rv[k];
        sA = D_C * sA + D_ETA * r;
        sB = D_C * sB + D_ETA * (r * r);
        m *= D_C;
    }
    block_scan(m, sA, sB, mS, aS, bS);

    double em = 1.0, ea = 0.0, eb = 0.0;
    if (tid > 0) { em = mS[tid - 1]; ea = aS[tid - 1]; eb = bS[tid - 1]; }
    double A = em * A0[blockIdx.x] + ea;
    double B = em * B0[blockIdx.x] + eb;

    double dsum = 0.0;
    for (int k = 0; k < len; ++k) {
        double r = (double)rv[k];
        double dA = D_ETA * (r - A);
        double dB = D_ETA * (r * r - B);
        double var = B - A * A;
        if (var < D_EPS) var = D_EPS;
        double denom = var * sqrt(var);
        dsum += (B * dA - 0.5 * A * dB) / denom;
        A += dA;
        B += dB;
    }

#pragma unroll
    for (int off = 32; off > 0; off >>= 1) dsum += __shfl_down(dsum, off, 64);
    if ((tid & 63) == 0) wsum[tid >> 6] = dsum;
    __syncthreads();
    if (tid == 0) bsum[blockIdx.x] = wsum[0] + wsum[1] + wsum[2] + wsum[3];
}

// ---------------- K5: final reduction ----------------
__global__ __launch_bounds__(BLOCK) void k5_final(
    const double* __restrict__ bsum, int nb, int nrows, float* __restrict__ out)
{
    __shared__ double sh[BLOCK / 64];
    int tid = threadIdx.x;
    double s = 0.0;
    for (int i = tid; i < nb; i += BLOCK) s += bsum[i];
#pragma unroll
    for (int off = 32; off > 0; off >>= 1) s += __shfl_down(s, off, 64);
    if ((tid & 63) == 0) sh[tid >> 6] = s;
    __syncthreads();
    if (tid == 0) out[0] = (float)(-(sh[0] + sh[1] + sh[2] + sh[3]) / (double)nrows);
}

extern "C" void kernel_launch(void* const* d_in, const int* in_sizes, int n_in,
                              void* d_out, int out_size, void* d_ws, size_t ws_size,
                              hipStream_t stream)
{
    const float* w = (const float*)d_in[0];
    const float* x = (const float*)d_in[1];
    int nrows = in_sizes[0] / 16;
    int nb = (nrows + CHUNK - 1) / CHUNK;

    char* ws = (char*)d_ws;
    double* blkM = (double*)(ws + 64);
    double* blkA = blkM + nb;
    double* blkB = blkA + nb;
    double* A0   = blkB + nb;
    double* B0   = A0 + nb;
    double* bsum = B0 + nb;
    size_t off = 64 + (size_t)6 * nb * sizeof(double);
    off = (off + 255) & ~(size_t)255;
    float* Rws = nullptr;
    if (ws_size >= off + (size_t)nrows * sizeof(float))
        Rws = (float*)(ws + off);

    if (Rws) {
        k1_dots_agg<<<nb, BLOCK, 0, stream>>>(w, x, nrows, Rws, blkM, blkA, blkB);
    } else {
        k2_partials_fb<<<nb, BLOCK, 0, stream>>>(w, x, nrows, blkM, blkA, blkB);
    }
    k3_scan<<<1, BLOCK, 0, stream>>>(nb, blkM, blkA, blkB, A0, B0);
    k4_dsum<<<nb, BLOCK, 0, stream>>>(Rws, w, x, nrows, A0, B0, bsum);
    k5_final<<<1, BLOCK, 0, stream>>>(bsum, nb, nrows, (float*)d_out);
}